// Round 3
// baseline (128.591 us; speedup 1.0000x reference)
//
#include <hip/hip_runtime.h>
#include <hip/hip_bf16.h>

// Self_Attn_3D: B=8, H=W=64 (N=4096 tokens), C_IN=256, C_QK=32.
// out[b,n] = gamma * sum_m softmax(q_n.k_m) * vbar[b,m] + xbar[b,n]
//   vbar = x @ mean_j(Wv) + mean(bv);  xbar = mean_c(x)
// (channel-mean commutes through attention output -> scalar-V flash attention)
//
// R3: flash was latency-bound at 2 waves/SIMD (grid-limited). Static-max
// softmax => (l,o) partials are ADDITIVE, so split K range x2 across blocks:
// grid 1024 -> 4 waves/SIMD, explicit register prefetch pipeline, f32x2
// packed accumulation (v_pk_*_f32). Tiny combine kernel does g*o/l + xbar.

typedef _Float16 half8  __attribute__((ext_vector_type(8)));
typedef _Float16 half4v __attribute__((ext_vector_type(4)));
typedef float    f32x4  __attribute__((ext_vector_type(4)));
typedef float    f32x2  __attribute__((ext_vector_type(2)));

#define LOG2E 1.4426950408889634f

#if __has_builtin(__builtin_amdgcn_exp2f)
#define EXP2(x) __builtin_amdgcn_exp2f(x)
#else
#define EXP2(x) exp2f(x)
#endif

// ---------------------------------------------------------------------------
// prep: (a) Wfr = [Wq|Wk] f16 in MFMA-B-fragment order
//           Wfr[((ch*4+quad)*64 + col)*8 + j] = W[c=ch*32+quad*8+j][col]
//       (b) wvbar[256] = row-mean of Wv, (c) bvbar = mean(bv)
// grid 129 x 256
// ---------------------------------------------------------------------------
__global__ __launch_bounds__(256) void prep_kernel(
    const float* __restrict__ Wq, const float* __restrict__ Wk,
    const float* __restrict__ Wv, const float* __restrict__ bv,
    _Float16* __restrict__ Wfr, float* __restrict__ wvbar, float* __restrict__ bvbar)
{
  int bid = blockIdx.x, tid = threadIdx.x;
  if (bid < 64) {
    int col = bid, c = tid;
    float v = (col < 32) ? Wq[c * 32 + col] : Wk[c * 32 + (col - 32)];
    int ch = c >> 5, quad = (c >> 3) & 3, j = c & 7;
    Wfr[(size_t)((ch * 4 + quad) * 64 + col) * 8 + j] = (_Float16)v;
  } else if (bid < 128) {
    int row = (bid - 64) * 4 + (tid >> 6);
    int lane = tid & 63;
    const float* p = Wv + (size_t)row * 256 + lane * 4;
    float s = p[0] + p[1] + p[2] + p[3];
    #pragma unroll
    for (int off = 32; off >= 1; off >>= 1) s += __shfl_xor(s, off);
    if (lane == 0) wvbar[row] = s * (1.0f / 256.0f);
  } else {
    if (tid < 64) {
      const float* p = bv + tid * 4;
      float s = p[0] + p[1] + p[2] + p[3];
      #pragma unroll
      for (int off = 32; off >= 1; off >>= 1) s += __shfl_xor(s, off);
      if (tid == 0) bvbar[0] = s * (1.0f / 256.0f);
    }
  }
}

// ---------------------------------------------------------------------------
// proj: per 64-token tile: Qh=(x@Wq+bq)*log2e (f16), Kh=x@Wk+bk (f16),
//       vbar, xbar (f32). MFMA f16 16x16x32, A from LDS, B direct from Wfr.
// grid 512 x 256
// ---------------------------------------------------------------------------
__global__ __launch_bounds__(256) void proj_kernel(
    const float* __restrict__ x, const _Float16* __restrict__ Wfr,
    const float* __restrict__ bq, const float* __restrict__ bk,
    const float* __restrict__ wvbar, const float* __restrict__ bvbar,
    _Float16* __restrict__ Qh, _Float16* __restrict__ Kh,
    float* __restrict__ vbarO, float* __restrict__ xbarO)
{
  __shared__ _Float16 XT[64 * 264];   // 64 tokens x 256 f16, stride 264
  int tid = threadIdx.x, blk = blockIdx.x;
  size_t tok0 = (size_t)blk * 64;

  const float4* xg4 = (const float4*)x;
  #pragma unroll
  for (int i = 0; i < 16; ++i) {
    int f = i * 256 + tid;
    int tok = f >> 6, c4 = f & 63;
    float4 v = xg4[(size_t)blk * 4096 + f];
    half4v h;
    h.x = (_Float16)v.x; h.y = (_Float16)v.y; h.z = (_Float16)v.z; h.w = (_Float16)v.w;
    *(half4v*)&XT[tok * 264 + c4 * 4] = h;
  }
  __syncthreads();

  if (tid < 64) {
    float vs = 0.f, xs = 0.f;
    #pragma unroll 4
    for (int g = 0; g < 32; ++g) {
      half8 h = *(const half8*)&XT[tid * 264 + g * 8];
      #pragma unroll
      for (int j = 0; j < 8; ++j) {
        float xv = (float)h[j];
        vs += xv * wvbar[g * 8 + j];
        xs += xv;
      }
    }
    vbarO[tok0 + tid] = vs + bvbar[0];
    xbarO[tok0 + tid] = xs * (1.0f / 256.0f);
  }

  int lane = tid & 63, w = tid >> 6;
  int l15 = lane & 15, quad = lane >> 4;
  f32x4 acc[4] = {(f32x4){0,0,0,0},(f32x4){0,0,0,0},(f32x4){0,0,0,0},(f32x4){0,0,0,0}};
  #pragma unroll
  for (int ch = 0; ch < 8; ++ch) {
    half8 a = *(const half8*)&XT[(w * 16 + l15) * 264 + ch * 32 + quad * 8];
    #pragma unroll
    for (int ct = 0; ct < 4; ++ct) {
      half8 bf = *(const half8*)(Wfr + (size_t)((ch * 4 + quad) * 64 + ct * 16 + l15) * 8);
      acc[ct] = __builtin_amdgcn_mfma_f32_16x16x32_f16(a, bf, acc[ct], 0, 0, 0);
    }
  }
  #pragma unroll
  for (int ct = 0; ct < 4; ++ct) {
    int col = ct * 16 + l15;
    #pragma unroll
    for (int r = 0; r < 4; ++r) {
      int token = w * 16 + quad * 4 + r;
      if (ct < 2) {
        float val = (acc[ct][r] + bq[col]) * LOG2E;
        Qh[(tok0 + token) * 32 + col] = (_Float16)val;
      } else {
        float val = acc[ct][r] + bk[col - 32];
        Kh[(tok0 + token) * 32 + (col - 32)] = (_Float16)val;
      }
    }
  }
}

// ---------------------------------------------------------------------------
// flash v3: scalar-V attention, K-split x2, barrier-free, register-pipelined.
// blk = b*128 + qt*2 + ks : 64 Q-rows, K range [ks*2048, ks*2048+2048).
// Writes ADDITIVE partials (l,o) per Q row (static-max softmax: p=2^(s-88)).
// grid 1024 x 256 -> 4 blocks/CU -> 4 waves/SIMD.
// ---------------------------------------------------------------------------
__global__ __launch_bounds__(256, 4) void flash_kernel(
    const _Float16* __restrict__ Qh, const _Float16* __restrict__ Kh,
    const float* __restrict__ vbar,
    float* __restrict__ lpart, float* __restrict__ opart)
{
  int tid = threadIdx.x, blk = blockIdx.x;
  int ks = blk & 1, qt = (blk >> 1) & 63, b = blk >> 7;
  int lane = tid & 63, w = tid >> 6;
  int l15 = lane & 15, quad = lane >> 4;

  const _Float16* Qb = Qh + (size_t)b * 4096 * 32;
  const _Float16* Kb = Kh + (size_t)b * 4096 * 32 + (size_t)ks * 2048 * 32;
  const float* vb = vbar + (size_t)b * 4096 + ks * 2048;

  // per-wave Q fragment: A[m=lane&15][k=quad*8+j]
  int qrow = qt * 64 + w * 16 + l15;
  half8 aq = *(const half8*)(Qb + (size_t)qrow * 32 + quad * 8);

  const f32x4 cinit = {-88.f, -88.f, -88.f, -88.f};
  // B-fragment base for this lane: K row (ct*16+l15), halves quad*8..+7
  const _Float16* kfrag = Kb + (size_t)l15 * 32 + quad * 8;
  const float* vfrag = vb + l15;

  f32x2 lacc[4] = {(f32x2){0,0},(f32x2){0,0},(f32x2){0,0},(f32x2){0,0}};
  f32x2 oacc[4] = {(f32x2){0,0},(f32x2){0,0},(f32x2){0,0},(f32x2){0,0}};

  // software pipeline: current tile in kc/vc, prefetch next into kn/vn
  half8 kc0, kc1, kc2, kc3;
  float vc0, vc1, vc2, vc3;
  kc0 = *(const half8*)(kfrag + 0 * 512);
  kc1 = *(const half8*)(kfrag + 1 * 512);
  kc2 = *(const half8*)(kfrag + 2 * 512);
  kc3 = *(const half8*)(kfrag + 3 * 512);
  vc0 = vfrag[0]; vc1 = vfrag[16]; vc2 = vfrag[32]; vc3 = vfrag[48];

  for (int kt = 0; kt < 32; ++kt) {
    half8 kn0, kn1, kn2, kn3;
    float vn0, vn1, vn2, vn3;
    if (kt < 31) {
      const _Float16* kf = kfrag + (size_t)(kt + 1) * 2048;
      const float* vf = vfrag + (kt + 1) * 64;
      kn0 = *(const half8*)(kf + 0 * 512);
      kn1 = *(const half8*)(kf + 1 * 512);
      kn2 = *(const half8*)(kf + 2 * 512);
      kn3 = *(const half8*)(kf + 3 * 512);
      vn0 = vf[0]; vn1 = vf[16]; vn2 = vf[32]; vn3 = vf[48];
    }
    f32x4 s0 = __builtin_amdgcn_mfma_f32_16x16x32_f16(aq, kc0, cinit, 0, 0, 0);
    f32x4 s1 = __builtin_amdgcn_mfma_f32_16x16x32_f16(aq, kc1, cinit, 0, 0, 0);
    f32x4 s2 = __builtin_amdgcn_mfma_f32_16x16x32_f16(aq, kc2, cinit, 0, 0, 0);
    f32x4 s3 = __builtin_amdgcn_mfma_f32_16x16x32_f16(aq, kc3, cinit, 0, 0, 0);
    f32x2 va = {vc0, vc1}, vbp = {vc2, vc3};
    #pragma unroll
    for (int r = 0; r < 4; ++r) {   // rows quad*4+r; cols ct*16+(lane&15)
      f32x2 pa = {EXP2(s0[r]), EXP2(s1[r])};
      f32x2 pb = {EXP2(s2[r]), EXP2(s3[r])};
      lacc[r] += pa + pb;           // v_pk_add_f32
      oacc[r] += pa * va;           // v_pk_fma_f32
      oacc[r] += pb * vbp;
    }
    kc0 = kn0; kc1 = kn1; kc2 = kn2; kc3 = kn3;
    vc0 = vn0; vc1 = vn1; vc2 = vn2; vc3 = vn3;
  }

  // reduce lane partials: pack (l,o) and butterfly over the 16 l15 lanes
  #pragma unroll
  for (int r = 0; r < 4; ++r) {
    float ls = lacc[r].x + lacc[r].y;
    float os = oacc[r].x + oacc[r].y;
    #pragma unroll
    for (int off = 1; off < 16; off <<= 1) {
      ls += __shfl_xor(ls, off);
      os += __shfl_xor(os, off);
    }
    if (l15 == 0) {
      int row = qt * 64 + w * 16 + quad * 4 + r;
      size_t idx = (size_t)ks * 32768 + (size_t)b * 4096 + row;
      lpart[idx] = ls;
      opart[idx] = os;
    }
  }
}

// ---------------------------------------------------------------------------
// combine: out = gamma * (o0+o1)/(l0+l1) + xbar.  grid 128 x 256
// ---------------------------------------------------------------------------
__global__ __launch_bounds__(256) void combine_kernel(
    const float* __restrict__ lpart, const float* __restrict__ opart,
    const float* __restrict__ xbar, const float* __restrict__ gamma,
    float* __restrict__ out)
{
  int i = blockIdx.x * 256 + threadIdx.x;
  float l = lpart[i] + lpart[32768 + i];
  float o = opart[i] + opart[32768 + i];
  out[i] = gamma[0] * (o / l) + xbar[i];
}

// ---------------------------------------------------------------------------
extern "C" void kernel_launch(void* const* d_in, const int* in_sizes, int n_in,
                              void* d_out, int out_size, void* d_ws, size_t ws_size,
                              hipStream_t stream)
{
  const float* x     = (const float*)d_in[0];
  const float* Wq    = (const float*)d_in[1];
  const float* bq    = (const float*)d_in[2];
  const float* Wk    = (const float*)d_in[3];
  const float* bk    = (const float*)d_in[4];
  const float* Wv    = (const float*)d_in[5];
  const float* bv    = (const float*)d_in[6];
  const float* gamma = (const float*)d_in[7];
  float* out = (float*)d_out;

  char* ws = (char*)d_ws;                                    // ~5 MB used
  _Float16* Wfr  = (_Float16*)(ws);                          // 32 KB
  float* wvbar   = (float*)(ws + 32768);                     // 1 KB
  float* bvbar   = (float*)(ws + 33792);                     // 4 B
  _Float16* Qh   = (_Float16*)(ws + 65536);                  // 2 MB
  _Float16* Kh   = (_Float16*)(ws + 65536 + 2097152);        // 2 MB
  float* vbarA   = (float*)(ws + 65536 + 4194304);           // 128 KB
  float* xbarA   = (float*)(ws + 65536 + 4194304 + 131072);  // 128 KB
  float* lpart   = (float*)(ws + 65536 + 4194304 + 262144);  // 256 KB (2 x 32K f32)
  float* opart   = (float*)(ws + 65536 + 4194304 + 524288);  // 256 KB

  prep_kernel<<<129, 256, 0, stream>>>(Wq, Wk, Wv, bv, Wfr, wvbar, bvbar);
  proj_kernel<<<512, 256, 0, stream>>>(x, Wfr, bq, bk, wvbar, bvbar, Qh, Kh, vbarA, xbarA);
  flash_kernel<<<1024, 256, 0, stream>>>(Qh, Kh, vbarA, lpart, opart);
  combine_kernel<<<128, 256, 0, stream>>>(lpart, opart, xbarA, gamma, out);
}

// Round 4
// 126.957 us; speedup vs baseline: 1.0129x; 1.0129x over previous
//
#include <hip/hip_runtime.h>
#include <hip/hip_bf16.h>

// Self_Attn_3D: B=8, H=W=64 (N=4096 tokens), C_IN=256, C_QK=32.
// out[b,n] = gamma * sum_m softmax(q_n.k_m) * vbar[b,m] + xbar[b,n]
//   vbar = x @ mean_j(Wv) + mean(bv);  xbar = mean_c(x)
// (channel-mean commutes through attention output -> scalar-V flash attention)
//
// R4: 3 dispatches. proj is LDS/barrier-free: MFMA A-fragments read directly
// from global x; vbar/xbar computed via 2 extra MFMA B-columns (wvbar, 1/256).
// flash does K-split x2 INSIDE the block (8 waves = 4 Q-subtiles x 2 K-halves),
// one LDS reduce, writes out directly (combine kernel eliminated).
// Evidence says ~100us of dur_us is harness reset (ws fill 43us + restores);
// kernel-side total is ~25us -> this round minimizes the controllable part.

typedef _Float16 half8  __attribute__((ext_vector_type(8)));
typedef float    f32x4  __attribute__((ext_vector_type(4)));
typedef float    f32x2  __attribute__((ext_vector_type(2)));

#define LOG2E 1.4426950408889634f

#if __has_builtin(__builtin_amdgcn_exp2f)
#define EXP2(x) __builtin_amdgcn_exp2f(x)
#else
#define EXP2(x) exp2f(x)
#endif

// ---------------------------------------------------------------------------
// prep: (a) Wfr = [Wq|Wk] f16 in MFMA-B-fragment order
//           Wfr[((ch*4+quad)*64 + col)*8 + j] = W[c=ch*32+quad*8+j][col]
//       (b) wvbar rows-mean of Wv as f32 + f16, (c) bvbar = mean(bv)
// grid 129 x 256
// ---------------------------------------------------------------------------
__global__ __launch_bounds__(256) void prep_kernel(
    const float* __restrict__ Wq, const float* __restrict__ Wk,
    const float* __restrict__ Wv, const float* __restrict__ bv,
    _Float16* __restrict__ Wfr, float* __restrict__ wvbar,
    _Float16* __restrict__ wvbarH, float* __restrict__ bvbar)
{
  int bid = blockIdx.x, tid = threadIdx.x;
  if (bid < 64) {
    int col = bid, c = tid;
    float v = (col < 32) ? Wq[c * 32 + col] : Wk[c * 32 + (col - 32)];
    int ch = c >> 5, quad = (c >> 3) & 3, j = c & 7;
    Wfr[(size_t)((ch * 4 + quad) * 64 + col) * 8 + j] = (_Float16)v;
  } else if (bid < 128) {
    int row = (bid - 64) * 4 + (tid >> 6);
    int lane = tid & 63;
    const float* p = Wv + (size_t)row * 256 + lane * 4;
    float s = p[0] + p[1] + p[2] + p[3];
    #pragma unroll
    for (int off = 32; off >= 1; off >>= 1) s += __shfl_xor(s, off);
    if (lane == 0) {
      float m = s * (1.0f / 256.0f);
      wvbar[row] = m;
      wvbarH[row] = (_Float16)m;
    }
  } else {
    if (tid < 64) {
      const float* p = bv + tid * 4;
      float s = p[0] + p[1] + p[2] + p[3];
      #pragma unroll
      for (int off = 32; off >= 1; off >>= 1) s += __shfl_xor(s, off);
      if (tid == 0) bvbar[0] = s * (1.0f / 256.0f);
    }
  }
}

// ---------------------------------------------------------------------------
// proj v2: LDS/barrier-free. Each wave owns 16 tokens. Per K-chunk (32 ch):
//   A frag  = x[tok0+l15][ch*32+quad*8 .. +7]  (2 x float4 direct from global;
//             the wave's 64 lanes cover complete 128B lines)
//   5 MFMAs = Q cols 0-31 (2), K cols 0-31 (2), stats (1: col0=wvbar col1=1/256)
// Epilogue writes Qh (*log2e), Kh, vbar (+bvbar), xbar.
// grid 512 x 256  (2048 waves x 16 tokens = 32768 tokens)
// ---------------------------------------------------------------------------
__global__ __launch_bounds__(256) void proj_kernel(
    const float* __restrict__ x, const _Float16* __restrict__ Wfr,
    const _Float16* __restrict__ wvbarH,
    const float* __restrict__ bq, const float* __restrict__ bk,
    const float* __restrict__ bvbar,
    _Float16* __restrict__ Qh, _Float16* __restrict__ Kh,
    float* __restrict__ vbarO, float* __restrict__ xbarO)
{
  int tid = threadIdx.x, blk = blockIdx.x;
  int lane = tid & 63, w = tid >> 6;
  int l15 = lane & 15, quad = lane >> 4;
  size_t tok0 = (size_t)blk * 64 + w * 16;          // wave's first token (flat)

  const float* xrow = x + (tok0 + l15) * 256;       // lane's A-row base

  half8 c256h;
  #pragma unroll
  for (int j = 0; j < 8; ++j) c256h[j] = (_Float16)(1.0f / 256.0f);

  f32x4 accQ0 = {0,0,0,0}, accQ1 = {0,0,0,0};
  f32x4 accK0 = {0,0,0,0}, accK1 = {0,0,0,0};
  f32x4 accS  = {0,0,0,0};

  #pragma unroll
  for (int ch = 0; ch < 8; ++ch) {
    const float* ap = xrow + ch * 32 + quad * 8;
    float4 a0 = *(const float4*)ap;
    float4 a1 = *(const float4*)(ap + 4);
    half8 a;
    a[0] = (_Float16)a0.x; a[1] = (_Float16)a0.y;
    a[2] = (_Float16)a0.z; a[3] = (_Float16)a0.w;
    a[4] = (_Float16)a1.x; a[5] = (_Float16)a1.y;
    a[6] = (_Float16)a1.z; a[7] = (_Float16)a1.w;

    const _Float16* wb = Wfr + (size_t)((ch * 4 + quad) * 64 + l15) * 8;
    half8 b0 = *(const half8*)(wb + 0 * 16 * 8);
    half8 b1 = *(const half8*)(wb + 1 * 16 * 8);
    half8 b2 = *(const half8*)(wb + 2 * 16 * 8);
    half8 b3 = *(const half8*)(wb + 3 * 16 * 8);

    accQ0 = __builtin_amdgcn_mfma_f32_16x16x32_f16(a, b0, accQ0, 0, 0, 0);
    accQ1 = __builtin_amdgcn_mfma_f32_16x16x32_f16(a, b1, accQ1, 0, 0, 0);
    accK0 = __builtin_amdgcn_mfma_f32_16x16x32_f16(a, b2, accK0, 0, 0, 0);
    accK1 = __builtin_amdgcn_mfma_f32_16x16x32_f16(a, b3, accK1, 0, 0, 0);

    // stats B: col0 = wvbar chunk, col1 = 1/256, cols 2..15 = 0
    half8 wv8 = *(const half8*)(wvbarH + ch * 32 + quad * 8);  // broadcast/quad
    half8 bs = {0,0,0,0,0,0,0,0};
    if (l15 == 0) bs = wv8;
    if (l15 == 1) bs = c256h;
    accS = __builtin_amdgcn_mfma_f32_16x16x32_f16(a, bs, accS, 0, 0, 0);
  }

  // D layout: col = lane&15, row = quad*4 + r
  float bq0 = bq[l15], bq1 = bq[16 + l15];
  float bk0 = bk[l15], bk1 = bk[16 + l15];
  #pragma unroll
  for (int r = 0; r < 4; ++r) {
    size_t g = tok0 + quad * 4 + r;
    Qh[g * 32 + l15]      = (_Float16)((accQ0[r] + bq0) * LOG2E);
    Qh[g * 32 + 16 + l15] = (_Float16)((accQ1[r] + bq1) * LOG2E);
    Kh[g * 32 + l15]      = (_Float16)(accK0[r] + bk0);
    Kh[g * 32 + 16 + l15] = (_Float16)(accK1[r] + bk1);
  }
  if (l15 == 0) {
    float bvb = bvbar[0];
    #pragma unroll
    for (int r = 0; r < 4; ++r) vbarO[tok0 + quad * 4 + r] = accS[r] + bvb;
  }
  if (l15 == 1) {
    #pragma unroll
    for (int r = 0; r < 4; ++r) xbarO[tok0 + quad * 4 + r] = accS[r];
  }
}

// ---------------------------------------------------------------------------
// flash v4: scalar-V attention, K-split x2 inside the block.
// Block = 64 Q-rows of one batch; 8 waves = 4 Q-subtiles x 2 K-halves.
// Barrier-free main loop (direct global K reads, register-pipelined),
// one LDS reduce at the end, writes out = gamma*o/l + xbar directly.
// Static-max softmax: s = q.k*log2e - 88 via MFMA C bias; p = 2^s (additive).
// grid 512 x 512 -> 2 blocks/CU -> 4 waves/SIMD.
// ---------------------------------------------------------------------------
__global__ __launch_bounds__(512, 4) void flash_kernel(
    const _Float16* __restrict__ Qh, const _Float16* __restrict__ Kh,
    const float* __restrict__ vbar, const float* __restrict__ xbar,
    const float* __restrict__ gamma, float* __restrict__ out)
{
  __shared__ float lsm[2][64], osm[2][64];
  int tid = threadIdx.x, blk = blockIdx.x;
  int b = blk >> 6, qt = blk & 63;
  int lane = tid & 63, w = tid >> 6;       // w 0..7
  int qs = w & 3, kh = w >> 2;
  int l15 = lane & 15, quad = lane >> 4;

  const _Float16* Qb = Qh + (size_t)b * 4096 * 32;
  const _Float16* Kb = Kh + (size_t)b * 4096 * 32 + (size_t)kh * 2048 * 32;
  const float* vb = vbar + (size_t)b * 4096 + kh * 2048;

  // per-wave Q fragment: A[m=lane&15][k=quad*8+j]
  int qrow = qt * 64 + qs * 16 + l15;
  half8 aq = *(const half8*)(Qb + (size_t)qrow * 32 + quad * 8);

  const f32x4 cinit = {-88.f, -88.f, -88.f, -88.f};
  // B-fragment base: K row (ct*16+l15), halves quad*8..+7
  const _Float16* kfrag = Kb + (size_t)l15 * 32 + quad * 8;
  const float* vfrag = vb + l15;

  f32x2 lacc[4] = {(f32x2){0,0},(f32x2){0,0},(f32x2){0,0},(f32x2){0,0}};
  f32x2 oacc[4] = {(f32x2){0,0},(f32x2){0,0},(f32x2){0,0},(f32x2){0,0}};

  // register pipeline: current tile kc/vc, prefetch next into kn/vn
  half8 kc0, kc1, kc2, kc3;
  float vc0, vc1, vc2, vc3;
  kc0 = *(const half8*)(kfrag + 0 * 512);
  kc1 = *(const half8*)(kfrag + 1 * 512);
  kc2 = *(const half8*)(kfrag + 2 * 512);
  kc3 = *(const half8*)(kfrag + 3 * 512);
  vc0 = vfrag[0]; vc1 = vfrag[16]; vc2 = vfrag[32]; vc3 = vfrag[48];

  for (int kt = 0; kt < 32; ++kt) {
    half8 kn0, kn1, kn2, kn3;
    float vn0, vn1, vn2, vn3;
    if (kt < 31) {
      const _Float16* kf = kfrag + (size_t)(kt + 1) * 2048;
      const float* vf = vfrag + (kt + 1) * 64;
      kn0 = *(const half8*)(kf + 0 * 512);
      kn1 = *(const half8*)(kf + 1 * 512);
      kn2 = *(const half8*)(kf + 2 * 512);
      kn3 = *(const half8*)(kf + 3 * 512);
      vn0 = vf[0]; vn1 = vf[16]; vn2 = vf[32]; vn3 = vf[48];
    }
    f32x4 s0 = __builtin_amdgcn_mfma_f32_16x16x32_f16(aq, kc0, cinit, 0, 0, 0);
    f32x4 s1 = __builtin_amdgcn_mfma_f32_16x16x32_f16(aq, kc1, cinit, 0, 0, 0);
    f32x4 s2 = __builtin_amdgcn_mfma_f32_16x16x32_f16(aq, kc2, cinit, 0, 0, 0);
    f32x4 s3 = __builtin_amdgcn_mfma_f32_16x16x32_f16(aq, kc3, cinit, 0, 0, 0);
    f32x2 va = {vc0, vc1}, vbp = {vc2, vc3};
    #pragma unroll
    for (int r = 0; r < 4; ++r) {   // rows quad*4+r; cols ct*16+(lane&15)
      f32x2 pa = {EXP2(s0[r]), EXP2(s1[r])};
      f32x2 pb = {EXP2(s2[r]), EXP2(s3[r])};
      lacc[r] += pa + pb;           // v_pk_add_f32
      oacc[r] += pa * va;           // v_pk_fma_f32
      oacc[r] += pb * vbp;
    }
    kc0 = kn0; kc1 = kn1; kc2 = kn2; kc3 = kn3;
    vc0 = vn0; vc1 = vn1; vc2 = vn2; vc3 = vn3;
  }

  // butterfly over the 16 col-lanes, then LDS combine of the two K-halves
  #pragma unroll
  for (int r = 0; r < 4; ++r) {
    float ls = lacc[r].x + lacc[r].y;
    float os = oacc[r].x + oacc[r].y;
    #pragma unroll
    for (int off = 1; off < 16; off <<= 1) {
      ls += __shfl_xor(ls, off);
      os += __shfl_xor(os, off);
    }
    if (l15 == 0) {
      int rr = qs * 16 + quad * 4 + r;
      lsm[kh][rr] = ls;
      osm[kh][rr] = os;
    }
  }
  __syncthreads();
  if (tid < 64) {
    float l = lsm[0][tid] + lsm[1][tid];
    float o = osm[0][tid] + osm[1][tid];
    size_t idx = (size_t)b * 4096 + qt * 64 + tid;
    out[idx] = gamma[0] * (o / l) + xbar[idx];
  }
}

// ---------------------------------------------------------------------------
extern "C" void kernel_launch(void* const* d_in, const int* in_sizes, int n_in,
                              void* d_out, int out_size, void* d_ws, size_t ws_size,
                              hipStream_t stream)
{
  const float* x     = (const float*)d_in[0];
  const float* Wq    = (const float*)d_in[1];
  const float* bq    = (const float*)d_in[2];
  const float* Wk    = (const float*)d_in[3];
  const float* bk    = (const float*)d_in[4];
  const float* Wv    = (const float*)d_in[5];
  const float* bv    = (const float*)d_in[6];
  const float* gamma = (const float*)d_in[7];
  float* out = (float*)d_out;

  char* ws = (char*)d_ws;                                    // ~4.6 MB used
  _Float16* Wfr    = (_Float16*)(ws);                        // 32 KB
  float* wvbar     = (float*)(ws + 32768);                   // 1 KB
  _Float16* wvbarH = (_Float16*)(ws + 33792);                // 512 B
  float* bvbar     = (float*)(ws + 34304);                   // 4 B
  _Float16* Qh     = (_Float16*)(ws + 65536);                // 2 MB
  _Float16* Kh     = (_Float16*)(ws + 65536 + 2097152);      // 2 MB
  float* vbarA     = (float*)(ws + 65536 + 4194304);         // 128 KB
  float* xbarA     = (float*)(ws + 65536 + 4194304 + 131072);// 128 KB

  prep_kernel<<<129, 256, 0, stream>>>(Wq, Wk, Wv, bv, Wfr, wvbar, wvbarH, bvbar);
  proj_kernel<<<512, 256, 0, stream>>>(x, Wfr, wvbarH, bq, bk, bvbar, Qh, Kh, vbarA, xbarA);
  flash_kernel<<<512, 512, 0, stream>>>(Qh, Kh, vbarA, xbarA, gamma, out);
}